// Round 9
// baseline (351.032 us; speedup 1.0000x reference)
//
#include <hip/hip_runtime.h>
#include <math.h>

// Problem constants
#define D_MODEL 2048
#define HD      128
#define NB      4
#define TT      4096
#define M_TOT   (NB * TT)   // 16384
#define NCHB    80          // causal s-chunks per batch at BQ=128, CHT=16
#define CHT     16          // s-tiles (of 64 keys) per chunk

typedef __attribute__((ext_vector_type(8))) short bf16x8;   // 8 bf16 = 4 VGPRs
typedef __attribute__((ext_vector_type(4))) float f32x4;

__device__ __forceinline__ ushort f2bf(float f) {
    union { float f; unsigned int u; } v; v.f = f;
    unsigned int u = v.u;
    unsigned int r = (u + 0x7FFFu + ((u >> 16) & 1u)) >> 16;   // RNE
    return (ushort)r;
}

// async global->LDS DMA, 16B per lane. LDS dst = wave-uniform base + lane*16.
__device__ __forceinline__ void gload_lds16(const void* g, void* l) {
    __builtin_amdgcn_global_load_lds(
        (const __attribute__((address_space(1))) unsigned int*)g,
        (__attribute__((address_space(3))) unsigned int*)l, 16, 0, 0);
}

// ---------------------------------------------------------------------------
// Kernel 1: WT[p][n][k] = bf16(W_p[k][n]) via LDS tile transpose.
// ---------------------------------------------------------------------------
__global__ __launch_bounds__(256) void wt_kernel(
        const float* __restrict__ Wq, const float* __restrict__ Wk,
        const float* __restrict__ Wv, ushort* __restrict__ WT) {
    const int p  = blockIdx.y;
    const int k0 = blockIdx.x * 128;
    const float* W = (p == 0) ? Wq : ((p == 1) ? Wk : Wv);

    __shared__ ushort Ts[128 * 136];   // [n][kk], stride 272B (16B-aligned rows)

    const int tid = threadIdx.x;
    for (int i = 0; i < 64; i++) {
        int c  = i * 256 + tid;
        int kk = c >> 7, n = c & 127;
        Ts[n * 136 + kk] = f2bf(W[(size_t)(k0 + kk) * 128 + n]);
    }
    __syncthreads();
    for (int i = 0; i < 8; i++) {
        int c = i * 256 + tid;
        int n = c >> 4, j = c & 15;
        *(uint4*)(WT + (size_t)p * (128 * 2048) + (size_t)n * 2048 + k0 + j * 8) =
            *(const uint4*)&Ts[n * 136 + j * 8];
    }
}

// ---------------------------------------------------------------------------
// Kernel 2: fused QKV projection.
// THIS ROUND (r8 decomposition: pipeline improved per-block latency 11.5k ->
// 9.2k cy/macro but 80KB LDS -> 2 blocks/CU -> 1.5 generations ate the win;
// constraint is GRID <= CO-RESIDENT SLOTS):
//  * NO B STAGING AT ALL. WT is 1.5MB, L2-resident on every XCD; b-fragments
//    are read directly from global (16B per lane, 64B-coalesced per quad
//    group, all L2 hits). Eliminates the B-DMA, its drains, and 64KB of LDS.
//  * LDS = As only (padded 64x136, 17.4KB) -> 4 blocks/CU -> all 768 blocks
//    in ONE generation with 16 waves/CU of TLP to hide b-load latency.
//  * Barriers: 2/macro protecting only the 8 ds_writes of As; areg(k+1)
//    global loads issued at macro top, covered by the micro loop.
//  * __launch_bounds__(256,4) caps VGPR at 128 (est ~115, no spill).
// ---------------------------------------------------------------------------
__global__ __launch_bounds__(256, 4) void proj_fused(
        const float* __restrict__ x, const ushort* __restrict__ WT,
        const float* __restrict__ bq, const float* __restrict__ bk, const float* __restrict__ bv,
        ushort* __restrict__ Qb, ushort* __restrict__ Kb, ushort* __restrict__ Vt) {
    const int bx0  = blockIdx.x;
    const int l    = (bx0 & 7) * 96 + (bx0 >> 3);  // XCD-affine logical id
    const int row0 = (l / 3) * 64;
    const int p    = l % 3;                        // col third == projection index
    const ushort* Wp   = WT + (size_t)p * (128 * 2048);
    const float*  bias = (p == 0) ? bq : ((p == 1) ? bk : bv);

    __shared__ ushort As[64 * 136];    // [m][k0..k0+128), stride 272B, conflict-free

    const int tid  = threadIdx.x;
    const int lane = tid & 63;
    const int wv   = tid >> 6;        // 0..3
    const int rw   = wv >> 1;         // row half (32 rows)
    const int cw   = wv & 1;          // col half (64 cols)
    const int quad = lane >> 4;
    const int ln16 = lane & 15;

    // A plan: 2048 float4 per macro, 8 per thread (rows read as 512B runs)
    int arow[8], apos[8];
    for (int i = 0; i < 8; i++) {
        int c = i * 256 + tid;
        arow[i] = c >> 5;
        apos[i] = c & 31;
    }

    // B fragment bases: column n = cw*64 + nt*16 + ln16, chunk (mi*4+quad)*8
    const ushort* bptr[4];
    for (int nt = 0; nt < 4; nt++) {
        int n = cw * 64 + nt * 16 + ln16;
        bptr[nt] = Wp + (size_t)n * 2048 + quad * 8;
    }

    f32x4 acc[2][4];
    for (int m2 = 0; m2 < 2; m2++)
        for (int nt = 0; nt < 4; nt++)
            acc[m2][nt] = (f32x4){0.f, 0.f, 0.f, 0.f};

    // prologue: A(0) -> regs -> As
    float4 areg[8];
    for (int i = 0; i < 8; i++)
        areg[i] = *(const float4*)(x + (size_t)(row0 + arow[i]) * D_MODEL + apos[i] * 4);
    for (int i = 0; i < 8; i++) {
        ushort4 o;
        o.x = f2bf(areg[i].x); o.y = f2bf(areg[i].y);
        o.z = f2bf(areg[i].z); o.w = f2bf(areg[i].w);
        *(ushort4*)&As[arow[i] * 136 + apos[i] * 4] = o;
    }
    __syncthreads();   // As(0) visible

    for (int k0 = 0; k0 < D_MODEL; k0 += 128) {
        const bool pf = (k0 + 128 < D_MODEL);
        if (pf)   // issue next macro's A loads; consumed only after the barrier
            for (int i = 0; i < 8; i++)
                areg[i] = *(const float4*)(x + (size_t)(row0 + arow[i]) * D_MODEL
                                             + k0 + 128 + apos[i] * 4);

        #pragma unroll
        for (int mi = 0; mi < 4; mi++) {
            bf16x8 a[2], b[4];
            for (int m2 = 0; m2 < 2; m2++)
                a[m2] = *(const bf16x8*)&As[(rw * 32 + m2 * 16 + ln16) * 136 + mi * 32 + quad * 8];
            for (int nt = 0; nt < 4; nt++)
                b[nt] = *(const bf16x8*)(bptr[nt] + k0 + mi * 32);   // L2-hit global read
            for (int m2 = 0; m2 < 2; m2++)
                for (int nt = 0; nt < 4; nt++)
                    acc[m2][nt] = __builtin_amdgcn_mfma_f32_16x16x32_bf16(a[m2], b[nt], acc[m2][nt], 0, 0, 0);
        }

        __syncthreads();   // all waves done reading As(k0)
        if (pf)
            for (int i = 0; i < 8; i++) {
                ushort4 o;
                o.x = f2bf(areg[i].x); o.y = f2bf(areg[i].y);
                o.z = f2bf(areg[i].z); o.w = f2bf(areg[i].w);
                *(ushort4*)&As[arow[i] * 136 + apos[i] * 4] = o;
            }
        __syncthreads();   // As(k+1) visible
    }

    // Epilogue. C/D: col=lane&15, row=quad*4+reg. p is block-uniform.
    for (int nt = 0; nt < 4; nt++) {
        int h  = cw * 64 + nt * 16 + ln16;   // 0..127
        float bc = bias[h];
        for (int m2 = 0; m2 < 2; m2++) {
            int rbase = row0 + rw * 32 + m2 * 16 + quad * 4;
            if (p < 2) {
                ushort* O = (p == 0) ? Qb : Kb;
                for (int r = 0; r < 4; r++)
                    O[(size_t)(rbase + r) * HD + h] = f2bf(acc[m2][nt][r] + bc);
            } else {
                int b = rbase >> 12;
                int t = rbase & 4095;
                ushort4 o;
                o.x = f2bf(acc[m2][nt][0] + bc);
                o.y = f2bf(acc[m2][nt][1] + bc);
                o.z = f2bf(acc[m2][nt][2] + bc);
                o.w = f2bf(acc[m2][nt][3] + bc);
                *(ushort4*)(Vt + ((size_t)b * HD + h) * TT + t) = o;
            }
        }
    }
}

// ---------------------------------------------------------------------------
// Kernel 3: split-s flash attention partials. (unchanged from r7: BQ=128,
// 8 waves, fixed-base softmax; 306.6->296.9 with it.)
// ---------------------------------------------------------------------------
#define SCALE2 0.12751744573223862f   // log2(e)/sqrt(128)

__global__ __launch_bounds__(512, 4) void attn_part(
        const ushort* __restrict__ Qb, const ushort* __restrict__ Kb,
        const ushort* __restrict__ Vt, float* __restrict__ Opart,
        float* __restrict__ Mpart, float* __restrict__ Lpart) {
    const int blk = blockIdx.x;
    const int bb  = blk & 3;
    const int cid = blk >> 2;          // ascending == qt2 descending (heavy first)

    int rem = cid, qt2 = 31;
    for (;;) {
        int cnt = (2 * qt2 + 17) >> 4;   // ceil((2*qt2+2)/16)
        if (rem < cnt) break;
        rem -= cnt; --qt2;
    }
    const int ch    = rem;
    const int st_lo = ch * CHT;
    const int st_hi = min(2 * qt2 + 2, st_lo + CHT);
    const int q0    = qt2 * 128;

    __shared__ ushort Ks[2][64 * 128];   // [s][h]; slot j holds chunk j^(s&15)
    __shared__ ushort Vs[2][128 * 64];   // [h][s]; slot j holds chunk j^(h&7)
    __shared__ ushort Ps[128 * 64];      // [q][s]; slot j holds chunk j^(q&7)

    const int tid  = threadIdx.x;
    const int lane = tid & 63;
    const int wv   = tid >> 6;          // 0..7
    const int quad = lane >> 4;
    const int ln16 = lane & 15;
    const int sw8  = ln16 & 7;

    // DMA plans: K 1024 chunks, V 1024 chunks (16B each), 2 each per thread
    int koff[2], voff[2], ldso[2];
    for (int i = 0; i < 2; i++) {
        int c = i * 512 + tid;
        { int r = c >> 4, j = c & 15, kc = j ^ (r & 15);
          koff[i] = r * HD + kc * 8; }
        { int h = c >> 3, j = c & 7, kc = j ^ (h & 7);
          voff[i] = h * TT + kc * 8; }
        ldso[i] = (i * 512 + wv * 64) * 8;    // wave-uniform LDS chunk base
    }
    const ushort* kbase = Kb + (size_t)bb * TT * HD;
    const ushort* vbase = Vt + (size_t)bb * HD * TT;

    // prologue: DMA first tile into buf 0; Q frags into registers meanwhile
    {
        const int s0 = st_lo * 64;
        for (int i = 0; i < 2; i++) gload_lds16(kbase + (size_t)s0 * HD + koff[i], &Ks[0][ldso[i]]);
        for (int i = 0; i < 2; i++) gload_lds16(vbase + s0 + voff[i], &Vs[0][ldso[i]]);
    }
    bf16x8 qf[4];
    {
        const ushort* qrow = Qb + (size_t)(bb * TT + q0 + 16 * wv + ln16) * HD;
        for (int kc = 0; kc < 4; kc++)
            qf[kc] = *(const bf16x8*)(qrow + kc * 32 + quad * 8);
    }

    f32x4 o_acc[8];
    for (int nt = 0; nt < 8; nt++) o_acc[nt] = (f32x4){0.f, 0.f, 0.f, 0.f};
    float lsum[4];
    for (int r = 0; r < 4; r++) lsum[r] = 0.f;

    __syncthreads();   // first tile's DMA drained

    for (int st = st_lo; st < st_hi; st++) {
        const int s0  = st * 64;
        const int buf = (st - st_lo) & 1;

        // issue next tile's DMA into the other buffer BEFORE computing
        if (st + 1 < st_hi) {
            const int s1 = s0 + 64;
            for (int i = 0; i < 2; i++) gload_lds16(kbase + (size_t)s1 * HD + koff[i], &Ks[buf ^ 1][ldso[i]]);
            for (int i = 0; i < 2; i++) gload_lds16(vbase + s1 + voff[i], &Vs[buf ^ 1][ldso[i]]);
        }

        // ---- S = Q K^T ----
        f32x4 sacc[4];
        for (int nt = 0; nt < 4; nt++) sacc[nt] = (f32x4){0.f, 0.f, 0.f, 0.f};
        for (int kc = 0; kc < 4; kc++) {
            int lc = kc * 4 + quad;
            for (int nt = 0; nt < 4; nt++) {
                int r = nt * 16 + ln16;
                bf16x8 b = *(const bf16x8*)&Ks[buf][r * 128 + ((lc ^ ln16) * 8)];
                sacc[nt] = __builtin_amdgcn_mfma_f32_16x16x32_bf16(qf[kc], b, sacc[nt], 0, 0, 0);
            }
        }

        // ---- fixed-base softmax: p = 2^(s*SCALE2), no max tracking ----
        const bool diag = (st >= 2 * qt2);
        for (int r = 0; r < 4; r++) {
            for (int nt = 0; nt < 4; nt++) {
                float s = sacc[nt][r] * SCALE2;
                if (diag) {
                    int sg = s0 + nt * 16 + ln16;
                    int qg = q0 + 16 * wv + quad * 4 + r;
                    if (sg > qg) s = -INFINITY;
                }
                float pv = exp2f(s);
                sacc[nt][r] = pv;
                lsum[r] += pv;          // per-lane partial; reduced once at end
            }
        }

        // P -> LDS (swizzled; same-wave rows only, no barrier needed)
        for (int nt = 0; nt < 4; nt++)
            for (int r = 0; r < 4; r++) {
                int row = 16 * wv + quad * 4 + r;
                int cj  = nt * 2 + (ln16 >> 3);
                Ps[row * 64 + ((cj ^ (row & 7)) * 8) + sw8] = f2bf(sacc[nt][r]);
            }

        // ---- O += P V ---- (reads Vs = V(st))
        for (int kc2 = 0; kc2 < 2; kc2++) {
            int lc = kc2 * 4 + quad;
            int prow = 16 * wv + ln16;
            bf16x8 a = *(const bf16x8*)&Ps[prow * 64 + ((lc ^ sw8) * 8)];
            for (int nt = 0; nt < 8; nt++) {
                int h = nt * 16 + ln16;
                bf16x8 b = *(const bf16x8*)&Vs[buf][h * 64 + ((lc ^ sw8) * 8)];
                o_acc[nt] = __builtin_amdgcn_mfma_f32_16x16x32_bf16(a, b, o_acc[nt], 0, 0, 0);
            }
        }

        __syncthreads();   // drains next tile's DMA; releases this buffer
    }

    // one l-reduce for the whole chunk
    for (int off = 8; off >= 1; off >>= 1)
        for (int r = 0; r < 4; r++)
            lsum[r] += __shfl_xor(lsum[r], off);

    // epilogue: unnormalized partial O + (m=0, l); slots are 128 rows
    const size_t slot = (size_t)bb * NCHB + cid;
    for (int nt = 0; nt < 8; nt++)
        for (int r = 0; r < 4; r++)
            Opart[(slot * 128 + 16 * wv + quad * 4 + r) * HD + nt * 16 + ln16] = o_acc[nt][r];
    if (ln16 == 0)
        for (int r = 0; r < 4; r++) {
            Mpart[slot * 128 + 16 * wv + quad * 4 + r] = 0.f;
            Lpart[slot * 128 + 16 * wv + quad * 4 + r] = lsum[r];
        }
}

// ---------------------------------------------------------------------------
// Kernel 4: merge partial chunks -> final output (fp32). 128-row slots;
// blockIdx.x is a 64-row granule (qt 0..63), mapped to (qt2, half).
// ---------------------------------------------------------------------------
__global__ __launch_bounds__(256) void merge_kernel(
        const float* __restrict__ Opart, const float* __restrict__ Mpart,
        const float* __restrict__ Lpart, float* __restrict__ out) {
    const int qt  = blockIdx.x;        // 64-row granule
    const int bb  = blockIdx.y;
    const int qt2 = qt >> 1;
    const int rh  = (qt & 1) * 64;     // row offset within the 128-row slot
    const int nch = (2 * qt2 + 17) >> 4;
    int base = 0;
    for (int j = 31; j > qt2; --j) base += (2 * j + 17) >> 4;

    const int tid = threadIdx.x;
    const int q0  = qt * 64;
    for (int e = tid; e < 64 * 32; e += 256) {
        int row = e >> 5;
        int c4  = e & 31;
        int srow = rh + row;
        float M = -INFINITY;
        float mv[4];
        for (int ch = 0; ch < nch; ch++) {
            mv[ch] = Mpart[((size_t)bb * NCHB + base + ch) * 128 + srow];
            M = fmaxf(M, mv[ch]);
        }
        float L = 0.f;
        float w[4];
        for (int ch = 0; ch < nch; ch++) {
            w[ch] = __expf(mv[ch] - M);
            L += w[ch] * Lpart[((size_t)bb * NCHB + base + ch) * 128 + srow];
        }
        float4 acc = {0.f, 0.f, 0.f, 0.f};
        for (int ch = 0; ch < nch; ch++) {
            const float4 o = *(const float4*)(Opart +
                (((size_t)bb * NCHB + base + ch) * 128 + srow) * HD + c4 * 4);
            acc.x += w[ch] * o.x; acc.y += w[ch] * o.y;
            acc.z += w[ch] * o.z; acc.w += w[ch] * o.w;
        }
        float invL = 1.f / L;
        float4 res = {acc.x * invL, acc.y * invL, acc.z * invL, acc.w * invL};
        *(float4*)(out + ((size_t)bb * TT + q0 + row) * HD + c4 * 4) = res;
    }
}

// ---------------------------------------------------------------------------
extern "C" void kernel_launch(void* const* d_in, const int* in_sizes, int n_in,
                              void* d_out, int out_size, void* d_ws, size_t ws_size,
                              hipStream_t stream) {
    const float* x  = (const float*)d_in[0];
    const float* Wq = (const float*)d_in[1];
    const float* bq = (const float*)d_in[2];
    const float* Wk = (const float*)d_in[3];
    const float* bk = (const float*)d_in[4];
    const float* Wv = (const float*)d_in[5];
    const float* bv = (const float*)d_in[6];
    float* out = (float*)d_out;

    ushort* WT = (ushort*)d_ws;
    ushort* Qb = WT + (size_t)3 * HD * D_MODEL;
    ushort* Kb = Qb + (size_t)M_TOT * HD;
    ushort* Vt = Kb + (size_t)M_TOT * HD;
    float* Opart = (float*)(Vt + (size_t)M_TOT * HD);
    float* Mpart = Opart + (size_t)NB * NCHB * 128 * HD;
    float* Lpart = Mpart + (size_t)NB * NCHB * 128;

    hipLaunchKernelGGL(wt_kernel, dim3(16, 3), dim3(256), 0, stream, Wq, Wk, Wv, WT);
    hipLaunchKernelGGL(proj_fused, dim3(768), dim3(256), 0, stream,
                       x, WT, bq, bk, bv, Qb, Kb, Vt);
    hipLaunchKernelGGL(attn_part, dim3(NB * NCHB), dim3(512), 0, stream,
                       Qb, Kb, Vt, Opart, Mpart, Lpart);
    hipLaunchKernelGGL(merge_kernel, dim3(64, NB), dim3(256), 0, stream,
                       Opart, Mpart, Lpart, out);
}

// Round 10
// 298.889 us; speedup vs baseline: 1.1745x; 1.1745x over previous
//
#include <hip/hip_runtime.h>
#include <math.h>

// Problem constants
#define D_MODEL 2048
#define HD      128
#define NB      4
#define TT      4096
#define M_TOT   (NB * TT)   // 16384
#define NCHB    63          // causal s-chunks per batch at BQ=128, CHT=22
#define CHT     22          // s-tiles (of 64 keys) per chunk; grid 252 <= 256 CUs

typedef __attribute__((ext_vector_type(8))) short bf16x8;   // 8 bf16 = 4 VGPRs
typedef __attribute__((ext_vector_type(4))) float f32x4;

__device__ __forceinline__ ushort f2bf(float f) {
    union { float f; unsigned int u; } v; v.f = f;
    unsigned int u = v.u;
    unsigned int r = (u + 0x7FFFu + ((u >> 16) & 1u)) >> 16;   // RNE
    return (ushort)r;
}

// async global->LDS DMA, 16B per lane. LDS dst = wave-uniform base + lane*16.
__device__ __forceinline__ void gload_lds16(const void* g, void* l) {
    __builtin_amdgcn_global_load_lds(
        (const __attribute__((address_space(1))) unsigned int*)g,
        (__attribute__((address_space(3))) unsigned int*)l, 16, 0, 0);
}

// ---------------------------------------------------------------------------
// Kernel 1: WT[p][n][k] = bf16(W_p[k][n]) via LDS tile transpose.
// ---------------------------------------------------------------------------
__global__ __launch_bounds__(256) void wt_kernel(
        const float* __restrict__ Wq, const float* __restrict__ Wk,
        const float* __restrict__ Wv, ushort* __restrict__ WT) {
    const int p  = blockIdx.y;
    const int k0 = blockIdx.x * 128;
    const float* W = (p == 0) ? Wq : ((p == 1) ? Wk : Wv);

    __shared__ ushort Ts[128 * 136];   // [n][kk], stride 272B (16B-aligned rows)

    const int tid = threadIdx.x;
    for (int i = 0; i < 64; i++) {
        int c  = i * 256 + tid;
        int kk = c >> 7, n = c & 127;
        Ts[n * 136 + kk] = f2bf(W[(size_t)(k0 + kk) * 128 + n]);
    }
    __syncthreads();
    for (int i = 0; i < 8; i++) {
        int c = i * 256 + tid;
        int n = c >> 4, j = c & 15;
        *(uint4*)(WT + (size_t)p * (128 * 2048) + (size_t)n * 2048 + k0 + j * 8) =
            *(const uint4*)&Ts[n * 136 + j * 8];
    }
}

// ---------------------------------------------------------------------------
// Kernel 2: fused QKV projection. EXACT r7 version (best measured: 77us).
// r8 (Bs dbuf, 80KB) = 91.8us: pipeline cut per-block latency 11.5k->9.2k
// cy/macro but 2 blocks/CU -> 1.5 generations ate the win. r9 (B direct
// from L2) = 130us: vmcnt chains per mi-step. r7's single-buffered DMA at
// 3 blocks/CU (one generation, 768 blocks) is the measured local optimum.
// ---------------------------------------------------------------------------
__global__ __launch_bounds__(256, 3) void proj_fused(
        const float* __restrict__ x, const ushort* __restrict__ WT,
        const float* __restrict__ bq, const float* __restrict__ bk, const float* __restrict__ bv,
        ushort* __restrict__ Qb, ushort* __restrict__ Kb, ushort* __restrict__ Vt) {
    const int bx0  = blockIdx.x;
    const int l    = (bx0 & 7) * 96 + (bx0 >> 3);  // XCD-affine logical id
    const int row0 = (l / 3) * 64;
    const int p    = l % 3;                        // col third == projection index
    const ushort* Wp   = WT + (size_t)p * (128 * 2048);
    const float*  bias = (p == 0) ? bq : ((p == 1) ? bk : bv);

    __shared__ ushort As[64 * 136];    // [m][k0..k0+128), stride 272B (17x16B, conflict-free)
    __shared__ ushort Bs[128 * 128];   // [n][k] unpadded; slot j holds chunk j^(n&15)

    const int tid  = threadIdx.x;
    const int lane = tid & 63;
    const int wv   = tid >> 6;        // 0..3
    const int rw   = wv >> 1;         // row half (32 rows)
    const int cw   = wv & 1;          // col half (64 cols)
    const int quad = lane >> 4;
    const int ln16 = lane & 15;

    // B DMA plan: 2048 chunks of 16B per macro, 8 per thread
    size_t  boff[8];
    ushort* bdst[8];
    for (int i = 0; i < 8; i++) {
        int c = i * 256 + tid;
        int n = c >> 4, j = c & 15;
        int kc = j ^ (n & 15);
        boff[i] = (size_t)n * 2048 + kc * 8;
        bdst[i] = &Bs[(i * 256 + wv * 64) * 8];   // wave-uniform base
    }
    // A plan: 2048 float4 per macro, 8 per thread (rows read as 512B runs)
    int arow[8], apos[8];
    for (int i = 0; i < 8; i++) {
        int c = i * 256 + tid;
        arow[i] = c >> 5;
        apos[i] = c & 31;
    }

    f32x4 acc[2][4];
    for (int m2 = 0; m2 < 2; m2++)
        for (int nt = 0; nt < 4; nt++)
            acc[m2][nt] = (f32x4){0.f, 0.f, 0.f, 0.f};

    float4 areg[8];
    for (int i = 0; i < 8; i++)
        areg[i] = *(const float4*)(x + (size_t)(row0 + arow[i]) * D_MODEL + apos[i] * 4);

    for (int k0 = 0; k0 < D_MODEL; k0 += 128) {
        __syncthreads();   // all waves done reading As/Bs of previous macro
        for (int i = 0; i < 8; i++)
            gload_lds16(Wp + boff[i] + k0, bdst[i]);
        for (int i = 0; i < 8; i++) {
            ushort4 o;
            o.x = f2bf(areg[i].x); o.y = f2bf(areg[i].y);
            o.z = f2bf(areg[i].z); o.w = f2bf(areg[i].w);
            *(ushort4*)&As[arow[i] * 136 + apos[i] * 4] = o;
        }
        __syncthreads();   // drain DMA (vm) + As writes (lgkm)
        if (k0 + 128 < D_MODEL)   // prefetch next macro's A (hidden by micro loop)
            for (int i = 0; i < 8; i++)
                areg[i] = *(const float4*)(x + (size_t)(row0 + arow[i]) * D_MODEL
                                             + k0 + 128 + apos[i] * 4);

        for (int mi = 0; mi < 4; mi++) {
            bf16x8 a[2], b[4];
            for (int m2 = 0; m2 < 2; m2++)
                a[m2] = *(const bf16x8*)&As[(rw * 32 + m2 * 16 + ln16) * 136 + mi * 32 + quad * 8];
            for (int nt = 0; nt < 4; nt++) {
                int n = cw * 64 + nt * 16 + ln16;
                int slot = (mi * 4 + quad) ^ (n & 15);
                b[nt] = *(const bf16x8*)&Bs[n * 128 + slot * 8];
            }
            for (int m2 = 0; m2 < 2; m2++)
                for (int nt = 0; nt < 4; nt++)
                    acc[m2][nt] = __builtin_amdgcn_mfma_f32_16x16x32_bf16(a[m2], b[nt], acc[m2][nt], 0, 0, 0);
        }
    }

    // Epilogue. C/D: col=lane&15, row=quad*4+reg. p is block-uniform.
    for (int nt = 0; nt < 4; nt++) {
        int h  = cw * 64 + nt * 16 + ln16;   // 0..127
        float bc = bias[h];
        for (int m2 = 0; m2 < 2; m2++) {
            int rbase = row0 + rw * 32 + m2 * 16 + quad * 4;
            if (p < 2) {
                ushort* O = (p == 0) ? Qb : Kb;
                for (int r = 0; r < 4; r++)
                    O[(size_t)(rbase + r) * HD + h] = f2bf(acc[m2][nt][r] + bc);
            } else {
                int b = rbase >> 12;
                int t = rbase & 4095;
                ushort4 o;
                o.x = f2bf(acc[m2][nt][0] + bc);
                o.y = f2bf(acc[m2][nt][1] + bc);
                o.z = f2bf(acc[m2][nt][2] + bc);
                o.w = f2bf(acc[m2][nt][3] + bc);
                *(ushort4*)(Vt + ((size_t)b * HD + h) * TT + t) = o;
            }
        }
    }
}

// ---------------------------------------------------------------------------
// Kernel 3: split-s flash attention partials.
// THIS ROUND: load-balance fix. r7's grid was 320 blocks at 2 blocks/CU ->
// 64 CUs ran 2 chunks, 192 ran 1; duration = 2x16 = 32 tile-times though
// average load was 1.25. CHT 16->22 gives 63 chunks/batch, grid 252 <= 256
// -> every CU runs <= 1 block; critical path = 22 tile-times (~0.69x).
// Inner loop unchanged (BQ=128, 8 waves, fixed-base softmax, dbuf DMA).
// ---------------------------------------------------------------------------
#define SCALE2 0.12751744573223862f   // log2(e)/sqrt(128)

__global__ __launch_bounds__(512, 4) void attn_part(
        const ushort* __restrict__ Qb, const ushort* __restrict__ Kb,
        const ushort* __restrict__ Vt, float* __restrict__ Opart,
        float* __restrict__ Mpart, float* __restrict__ Lpart) {
    const int blk = blockIdx.x;
    const int bb  = blk & 3;
    const int cid = blk >> 2;          // ascending == qt2 descending (heavy first)

    int rem = cid, qt2 = 31;
    for (;;) {
        int cnt = (2 * qt2 + 2 + CHT - 1) / CHT;   // ceil((2*qt2+2)/CHT)
        if (rem < cnt) break;
        rem -= cnt; --qt2;
    }
    const int ch    = rem;
    const int st_lo = ch * CHT;
    const int st_hi = min(2 * qt2 + 2, st_lo + CHT);
    const int q0    = qt2 * 128;

    __shared__ ushort Ks[2][64 * 128];   // [s][h]; slot j holds chunk j^(s&15)
    __shared__ ushort Vs[2][128 * 64];   // [h][s]; slot j holds chunk j^(h&7)
    __shared__ ushort Ps[128 * 64];      // [q][s]; slot j holds chunk j^(q&7)

    const int tid  = threadIdx.x;
    const int lane = tid & 63;
    const int wv   = tid >> 6;          // 0..7
    const int quad = lane >> 4;
    const int ln16 = lane & 15;
    const int sw8  = ln16 & 7;

    // DMA plans: K 1024 chunks, V 1024 chunks (16B each), 2 each per thread
    int koff[2], voff[2], ldso[2];
    for (int i = 0; i < 2; i++) {
        int c = i * 512 + tid;
        { int r = c >> 4, j = c & 15, kc = j ^ (r & 15);
          koff[i] = r * HD + kc * 8; }
        { int h = c >> 3, j = c & 7, kc = j ^ (h & 7);
          voff[i] = h * TT + kc * 8; }
        ldso[i] = (i * 512 + wv * 64) * 8;    // wave-uniform LDS chunk base
    }
    const ushort* kbase = Kb + (size_t)bb * TT * HD;
    const ushort* vbase = Vt + (size_t)bb * HD * TT;

    // prologue: DMA first tile into buf 0; Q frags into registers meanwhile
    {
        const int s0 = st_lo * 64;
        for (int i = 0; i < 2; i++) gload_lds16(kbase + (size_t)s0 * HD + koff[i], &Ks[0][ldso[i]]);
        for (int i = 0; i < 2; i++) gload_lds16(vbase + s0 + voff[i], &Vs[0][ldso[i]]);
    }
    bf16x8 qf[4];
    {
        const ushort* qrow = Qb + (size_t)(bb * TT + q0 + 16 * wv + ln16) * HD;
        for (int kc = 0; kc < 4; kc++)
            qf[kc] = *(const bf16x8*)(qrow + kc * 32 + quad * 8);
    }

    f32x4 o_acc[8];
    for (int nt = 0; nt < 8; nt++) o_acc[nt] = (f32x4){0.f, 0.f, 0.f, 0.f};
    float lsum[4];
    for (int r = 0; r < 4; r++) lsum[r] = 0.f;

    __syncthreads();   // first tile's DMA drained

    for (int st = st_lo; st < st_hi; st++) {
        const int s0  = st * 64;
        const int buf = (st - st_lo) & 1;

        // issue next tile's DMA into the other buffer BEFORE computing
        if (st + 1 < st_hi) {
            const int s1 = s0 + 64;
            for (int i = 0; i < 2; i++) gload_lds16(kbase + (size_t)s1 * HD + koff[i], &Ks[buf ^ 1][ldso[i]]);
            for (int i = 0; i < 2; i++) gload_lds16(vbase + s1 + voff[i], &Vs[buf ^ 1][ldso[i]]);
        }

        // ---- S = Q K^T ----
        f32x4 sacc[4];
        for (int nt = 0; nt < 4; nt++) sacc[nt] = (f32x4){0.f, 0.f, 0.f, 0.f};
        for (int kc = 0; kc < 4; kc++) {
            int lc = kc * 4 + quad;
            for (int nt = 0; nt < 4; nt++) {
                int r = nt * 16 + ln16;
                bf16x8 b = *(const bf16x8*)&Ks[buf][r * 128 + ((lc ^ ln16) * 8)];
                sacc[nt] = __builtin_amdgcn_mfma_f32_16x16x32_bf16(qf[kc], b, sacc[nt], 0, 0, 0);
            }
        }

        // ---- fixed-base softmax: p = 2^(s*SCALE2), no max tracking ----
        const bool diag = (st >= 2 * qt2);
        for (int r = 0; r < 4; r++) {
            for (int nt = 0; nt < 4; nt++) {
                float s = sacc[nt][r] * SCALE2;
                if (diag) {
                    int sg = s0 + nt * 16 + ln16;
                    int qg = q0 + 16 * wv + quad * 4 + r;
                    if (sg > qg) s = -INFINITY;
                }
                float pv = exp2f(s);
                sacc[nt][r] = pv;
                lsum[r] += pv;          // per-lane partial; reduced once at end
            }
        }

        // P -> LDS (swizzled; same-wave rows only, no barrier needed)
        for (int nt = 0; nt < 4; nt++)
            for (int r = 0; r < 4; r++) {
                int row = 16 * wv + quad * 4 + r;
                int cj  = nt * 2 + (ln16 >> 3);
                Ps[row * 64 + ((cj ^ (row & 7)) * 8) + sw8] = f2bf(sacc[nt][r]);
            }

        // ---- O += P V ---- (reads Vs = V(st))
        for (int kc2 = 0; kc2 < 2; kc2++) {
            int lc = kc2 * 4 + quad;
            int prow = 16 * wv + ln16;
            bf16x8 a = *(const bf16x8*)&Ps[prow * 64 + ((lc ^ sw8) * 8)];
            for (int nt = 0; nt < 8; nt++) {
                int h = nt * 16 + ln16;
                bf16x8 b = *(const bf16x8*)&Vs[buf][h * 64 + ((lc ^ sw8) * 8)];
                o_acc[nt] = __builtin_amdgcn_mfma_f32_16x16x32_bf16(a, b, o_acc[nt], 0, 0, 0);
            }
        }

        __syncthreads();   // drains next tile's DMA; releases this buffer
    }

    // one l-reduce for the whole chunk
    for (int off = 8; off >= 1; off >>= 1)
        for (int r = 0; r < 4; r++)
            lsum[r] += __shfl_xor(lsum[r], off);

    // epilogue: unnormalized partial O + (m=0, l); slots are 128 rows
    const size_t slot = (size_t)bb * NCHB + cid;
    for (int nt = 0; nt < 8; nt++)
        for (int r = 0; r < 4; r++)
            Opart[(slot * 128 + 16 * wv + quad * 4 + r) * HD + nt * 16 + ln16] = o_acc[nt][r];
    if (ln16 == 0)
        for (int r = 0; r < 4; r++) {
            Mpart[slot * 128 + 16 * wv + quad * 4 + r] = 0.f;
            Lpart[slot * 128 + 16 * wv + quad * 4 + r] = lsum[r];
        }
}

// ---------------------------------------------------------------------------
// Kernel 4: merge partial chunks -> final output (fp32). 128-row slots;
// blockIdx.x is a 64-row granule (qt 0..63), mapped to (qt2, half).
// nch <= 3 at CHT=22.
// ---------------------------------------------------------------------------
__global__ __launch_bounds__(256) void merge_kernel(
        const float* __restrict__ Opart, const float* __restrict__ Mpart,
        const float* __restrict__ Lpart, float* __restrict__ out) {
    const int qt  = blockIdx.x;        // 64-row granule
    const int bb  = blockIdx.y;
    const int qt2 = qt >> 1;
    const int rh  = (qt & 1) * 64;     // row offset within the 128-row slot
    const int nch = (2 * qt2 + 2 + CHT - 1) / CHT;
    int base = 0;
    for (int j = 31; j > qt2; --j) base += (2 * j + 2 + CHT - 1) / CHT;

    const int tid = threadIdx.x;
    const int q0  = qt * 64;
    for (int e = tid; e < 64 * 32; e += 256) {
        int row = e >> 5;
        int c4  = e & 31;
        int srow = rh + row;
        float M = -INFINITY;
        float mv[4];
        for (int ch = 0; ch < nch; ch++) {
            mv[ch] = Mpart[((size_t)bb * NCHB + base + ch) * 128 + srow];
            M = fmaxf(M, mv[ch]);
        }
        float L = 0.f;
        float w[4];
        for (int ch = 0; ch < nch; ch++) {
            w[ch] = __expf(mv[ch] - M);
            L += w[ch] * Lpart[((size_t)bb * NCHB + base + ch) * 128 + srow];
        }
        float4 acc = {0.f, 0.f, 0.f, 0.f};
        for (int ch = 0; ch < nch; ch++) {
            const float4 o = *(const float4*)(Opart +
                (((size_t)bb * NCHB + base + ch) * 128 + srow) * HD + c4 * 4);
            acc.x += w[ch] * o.x; acc.y += w[ch] * o.y;
            acc.z += w[ch] * o.z; acc.w += w[ch] * o.w;
        }
        float invL = 1.f / L;
        float4 res = {acc.x * invL, acc.y * invL, acc.z * invL, acc.w * invL};
        *(float4*)(out + ((size_t)bb * TT + q0 + row) * HD + c4 * 4) = res;
    }
}

// ---------------------------------------------------------------------------
extern "C" void kernel_launch(void* const* d_in, const int* in_sizes, int n_in,
                              void* d_out, int out_size, void* d_ws, size_t ws_size,
                              hipStream_t stream) {
    const float* x  = (const float*)d_in[0];
    const float* Wq = (const float*)d_in[1];
    const float* bq = (const float*)d_in[2];
    const float* Wk = (const float*)d_in[3];
    const float* bk = (const float*)d_in[4];
    const float* Wv = (const float*)d_in[5];
    const float* bv = (const float*)d_in[6];
    float* out = (float*)d_out;

    ushort* WT = (ushort*)d_ws;
    ushort* Qb = WT + (size_t)3 * HD * D_MODEL;
    ushort* Kb = Qb + (size_t)M_TOT * HD;
    ushort* Vt = Kb + (size_t)M_TOT * HD;
    float* Opart = (float*)(Vt + (size_t)M_TOT * HD);
    float* Mpart = Opart + (size_t)NB * NCHB * 128 * HD;
    float* Lpart = Mpart + (size_t)NB * NCHB * 128;

    hipLaunchKernelGGL(wt_kernel, dim3(16, 3), dim3(256), 0, stream, Wq, Wk, Wv, WT);
    hipLaunchKernelGGL(proj_fused, dim3(768), dim3(256), 0, stream,
                       x, WT, bq, bk, bv, Qb, Kb, Vt);
    hipLaunchKernelGGL(attn_part, dim3(NB * NCHB), dim3(512), 0, stream,
                       Qb, Kb, Vt, Opart, Mpart, Lpart);
    hipLaunchKernelGGL(merge_kernel, dim3(64, NB), dim3(256), 0, stream,
                       Opart, Mpart, Lpart, out);
}